// Round 1
// baseline (192.710 us; speedup 1.0000x reference)
//
#include <hip/hip_runtime.h>
#include <math.h>

typedef unsigned int  uint;
typedef unsigned short ushort;

// Problem constants
constexpr int NPTS = 30000;
constexpr int CIN  = 128;
constexpr int OC   = 128;   // O
constexpr int NH   = 8;     // heads
constexpr int NS   = 16;    // neighbors
constexpr int DH   = 16;    // O/H
constexpr int OSH  = 16;    // O/SHARE
constexpr float EPSF = 1e-5f;

typedef __attribute__((ext_vector_type(8))) __fp16 h8;
typedef __attribute__((ext_vector_type(4))) float  f32x4;
typedef __attribute__((ext_vector_type(2))) __fp16 h2;

__device__ __forceinline__ ushort f2h(float f) {
    __fp16 h = (__fp16)f;
    return *(ushort*)&h;
}
__device__ __forceinline__ uint pk2(float a, float b) {
    h2 v = __builtin_amdgcn_cvt_pkrtz(a, b);
    return *(uint*)&v;
}
__device__ __forceinline__ h2 asH2(uint u) { return *(h2*)&u; }

#if defined(__has_builtin)
#if __has_builtin(__builtin_elementwise_max)
#define PKMAX(a, b) __builtin_elementwise_max(a, b)
#endif
#endif
#ifndef PKMAX
__device__ __forceinline__ h2 PKMAX(h2 a, h2 b) {
    h2 r; r[0] = a[0] > b[0] ? a[0] : b[0]; r[1] = a[1] > b[1] ? a[1] : b[1]; return r;
}
#endif

// PACKS layout (uints):
constexpr int PK_WW1   = 0;     // 128: pairs (Ww1[2dp][o], Ww1[2dp+1][o]) at [dp*16+o] (kept for compat)
constexpr int PK_WP2   = 128;   // 192: c=0..2 pairs over o
constexpr int PK_BP2   = 320;   // 64
constexpr int PK_GW1   = 384;
constexpr int PK_BW1P  = 392;   // betaw1 pairs
constexpr int PK_GW2   = 400;
constexpr int PK_BW2P  = 408;   // betaw2 pairs
constexpr int PK_RM    = 416;   // rowmean(Ww2) pairs
constexpr int PKF_BW1  = 424;   // float view: bw1[16]
constexpr int PKF_RMB  = 440;   // float view: mean(bw2)

// ---------------------------------------------------------------------------
// Kernel 0: prep (tiny now — no x pass).
// Blocks [0,24): W{q,k,v} -> f16 transposed WT[o][k]; 8 blocks per mat.
// Block 24: PACKS.
// ---------------------------------------------------------------------------
__global__ __launch_bounds__(256) void prep_kernel(
    const float* __restrict__ Wq, const float* __restrict__ Wk, const float* __restrict__ Wv,
    const float* __restrict__ Wp2, const float* __restrict__ bp2,
    const float* __restrict__ gw1, const float* __restrict__ betaw1,
    const float* __restrict__ Ww1, const float* __restrict__ bw1,
    const float* __restrict__ gw2, const float* __restrict__ betaw2,
    const float* __restrict__ Ww2, const float* __restrict__ bw2,
    ushort* __restrict__ WT, uint* __restrict__ PK)
{
    const int b = blockIdx.x;
    const int t = threadIdx.x;
    if (b < 24) {
        const int mat = b >> 3;           // 0..2
        const int cg  = b & 7;            // col group of 16
        const float* W = (mat == 0) ? Wq : (mat == 1 ? Wk : Wv);
        const int col = cg * 16 + (t >> 4);
        const int k0  = (t & 15) * 8;
        float v0 = W[(k0 + 0) * OC + col], v1 = W[(k0 + 1) * OC + col];
        float v2 = W[(k0 + 2) * OC + col], v3 = W[(k0 + 3) * OC + col];
        float v4 = W[(k0 + 4) * OC + col], v5 = W[(k0 + 5) * OC + col];
        float v6 = W[(k0 + 6) * OC + col], v7 = W[(k0 + 7) * OC + col];
        uint4 u = make_uint4(pk2(v0, v1), pk2(v2, v3), pk2(v4, v5), pk2(v6, v7));
        *(uint4*)&WT[(size_t)mat * OC * CIN + (size_t)col * CIN + k0] = u;
    } else {
        float* FPK = (float*)PK;
        if (t < 128) {
            int dp = t >> 4, o = t & 15;
            PK[PK_WW1 + t] = pk2(Ww1[(2 * dp) * OSH + o], Ww1[(2 * dp + 1) * OSH + o]);
        }
        if (t < 192) {
            int c = t >> 6, jj = t & 63;
            PK[PK_WP2 + t] = pk2(Wp2[c * OC + 2 * jj], Wp2[c * OC + 2 * jj + 1]);
        }
        if (t < 64)
            PK[PK_BP2 + t] = pk2(bp2[2 * t], bp2[2 * t + 1]);
        if (t < 8) {
            PK[PK_GW1 + t]  = pk2(gw1[2 * t],    gw1[2 * t + 1]);
            PK[PK_BW1P + t] = pk2(betaw1[2 * t], betaw1[2 * t + 1]);
            PK[PK_GW2 + t]  = pk2(gw2[2 * t],    gw2[2 * t + 1]);
            PK[PK_BW2P + t] = pk2(betaw2[2 * t], betaw2[2 * t + 1]);
            float r0 = 0.f, r1 = 0.f;
            #pragma unroll
            for (int o2 = 0; o2 < OSH; ++o2) {
                r0 += Ww2[(2 * t) * OSH + o2];
                r1 += Ww2[(2 * t + 1) * OSH + o2];
            }
            PK[PK_RM + t] = pk2(r0 * (1.f / OSH), r1 * (1.f / OSH));
        }
        if (t < 16)
            FPK[PKF_BW1 + t] = bw1[t];
        if (t == 16) {
            float acc = 0.f;
            #pragma unroll
            for (int o2 = 0; o2 < OSH; ++o2) acc += bw2[o2];
            FPK[PKF_RMB] = acc * (1.f / OSH);
        }
    }
}

// ---------------------------------------------------------------------------
// Kernel 1: QKV projection via f16 MFMA (16x16x32), staging-free.
// (unchanged this round)
// ---------------------------------------------------------------------------
__global__ __launch_bounds__(256) void qkv_mfma(
    const float* __restrict__ x, const ushort* __restrict__ WT,
    const float* __restrict__ bq, const float* __restrict__ bk, const float* __restrict__ bv,
    ushort* __restrict__ yq, ushort* __restrict__ yk, ushort* __restrict__ yv)
{
    const int mat = blockIdx.y;
    const float* bias = (mat == 0) ? bq : (mat == 1 ? bk : bv);
    ushort* y         = (mat == 0) ? yq : (mat == 1 ? yk : yv);
    const ushort* T   = WT + (size_t)mat * OC * CIN;

    const int n0   = blockIdx.x * 128;
    const int t    = threadIdx.x;
    const int wave = t >> 6;
    const int lane = t & 63;
    const int m16  = lane & 15;
    const int quad = lane >> 4;

    f32x4 acc[2][8];
    #pragma unroll
    for (int mt = 0; mt < 2; ++mt)
        #pragma unroll
        for (int nt = 0; nt < 8; ++nt)
            acc[mt][nt] = (f32x4){0.f, 0.f, 0.f, 0.f};

    int r0i = n0 + wave * 32 + m16;      // A row for mt=0
    int r1i = r0i + 16;                  // A row for mt=1
    if (r0i > NPTS - 1) r0i = NPTS - 1;
    if (r1i > NPTS - 1) r1i = NPTS - 1;
    const float* arow0 = x + (size_t)r0i * CIN;
    const float* arow1 = x + (size_t)r1i * CIN;

    #pragma unroll
    for (int ks = 0; ks < 4; ++ks) {
        const int kb = ks * 32 + quad * 8;
        float4 f00 = *(const float4*)(arow0 + kb);
        float4 f01 = *(const float4*)(arow0 + kb + 4);
        float4 f10 = *(const float4*)(arow1 + kb);
        float4 f11 = *(const float4*)(arow1 + kb + 4);
        uint4 ua0 = make_uint4(pk2(f00.x, f00.y), pk2(f00.z, f00.w),
                               pk2(f01.x, f01.y), pk2(f01.z, f01.w));
        uint4 ua1 = make_uint4(pk2(f10.x, f10.y), pk2(f10.z, f10.w),
                               pk2(f11.x, f11.y), pk2(f11.z, f11.w));
        h8 a0 = *(h8*)&ua0;
        h8 a1 = *(h8*)&ua1;
        #pragma unroll
        for (int nt = 0; nt < 8; ++nt) {
            h8 bfr = *(const h8*)(T + (size_t)(nt * 16 + m16) * CIN + kb);
            acc[0][nt] = __builtin_amdgcn_mfma_f32_16x16x32_f16(a0, bfr, acc[0][nt], 0, 0, 0);
            acc[1][nt] = __builtin_amdgcn_mfma_f32_16x16x32_f16(a1, bfr, acc[1][nt], 0, 0, 0);
        }
    }

    #pragma unroll
    for (int mt = 0; mt < 2; ++mt) {
        #pragma unroll
        for (int nt = 0; nt < 8; ++nt) {
            const int col = nt * 16 + m16;
            const float bcol = bias[col];
            #pragma unroll
            for (int r = 0; r < 4; ++r) {
                int row = n0 + wave * 32 + mt * 16 + quad * 4 + r;
                if (row < NPTS)
                    y[(size_t)row * OC + col] = f2h(acc[mt][nt][r] + bcol);
            }
        }
    }
}

// ---------------------------------------------------------------------------
// Kernel 2: per-point attention.
// NEW this round: w1 = relu(LN1(r)) @ Ww1 + bw1 moved from 128x v_dot2 to
// 4x mfma_f32_16x16x32_f16 per wave (64 rows x 16 @ 16x16; K=16 real, upper
// 16 of B zeroed). Wave-local LDS round trips for fragment layout; one shared
// pool overlaid across phases (a2-stage / w1-buf / s_c) + extra barrier.
// Fragment mappings identical to the verified qkv_mfma usage:
//   A: row = lane&15, k = 8*(lane>>4)+i ; B: col = lane&15, same k
//   C: col = lane&15, row = (lane>>4)*4 + r
// ---------------------------------------------------------------------------
__global__ __launch_bounds__(128) void attn_kernel(
    const float* __restrict__ p, const int* __restrict__ idx,
    const ushort* __restrict__ xq, const ushort* __restrict__ xk, const ushort* __restrict__ xv,
    const float* __restrict__ Wp1, const float* __restrict__ bp1,
    const float* __restrict__ gp,  const float* __restrict__ betap,
    const float* __restrict__ Ww1,
    const uint* __restrict__ PK,
    float* __restrict__ out)
{
    const int n = blockIdx.x;
    const int t = threadIdx.x;   // 0..127
    const int s = t & 15;        // neighbor
    const int h = t >> 4;        // head 0..7
    const int lane = t & 63;
    const int wv   = t >> 6;

    const float* FPK = (const float*)PK;

    // One shared pool, phase-overlaid (10240 B):
    //   phase A (per wave, wave-local): a2 staging, 64 rows x 80 B at wv*5120
    //   phase B (per wave, wave-local): w1 f32 rows, same bytes
    //   phase C (block, after barrier): s_c[16][68] uints at pool base
    __shared__ __attribute__((aligned(16))) char pool[2 * 64 * 80];
    char* aw = pool + wv * (64 * 80);

    // --- B fragment of Ww1 for mfma 16x16x32 (K=16 real, upper 16 zero) ---
    h8 bfrag;
    {
        uint4 u = make_uint4(0u, 0u, 0u, 0u);
        const int c = lane & 15;
        const int q = lane >> 4;
        if (q < 2) {
            const float* wp = Ww1 + (q * 8) * OSH + c;   // Ww1[k][o], row-major
            u.x = pk2(wp[0 * OSH], wp[1 * OSH]);
            u.y = pk2(wp[2 * OSH], wp[3 * OSH]);
            u.z = pk2(wp[4 * OSH], wp[5 * OSH]);
            u.w = pk2(wp[6 * OSH], wp[7 * OSH]);
        }
        bfrag = *(h8*)&u;
    }

    const int j = idx[n * NS + s];

    // inline pr-MLP (3-wide): u = pr @ Wp1 + bp1; LN3; relu
    float t0, t1, t2;
    {
        float pr0 = p[j * 3 + 0] - p[n * 3 + 0];
        float pr1 = p[j * 3 + 1] - p[n * 3 + 1];
        float pr2 = p[j * 3 + 2] - p[n * 3 + 2];
        float u[3];
        #pragma unroll
        for (int c = 0; c < 3; ++c)
            u[c] = bp1[c] + pr0 * Wp1[0 * 3 + c] + pr1 * Wp1[1 * 3 + c] + pr2 * Wp1[2 * 3 + c];
        float m   = (u[0] + u[1] + u[2]) * (1.f / 3.f);
        float d0 = u[0] - m, d1 = u[1] - m, d2 = u[2] - m;
        float var = (d0 * d0 + d1 * d1 + d2 * d2) * (1.f / 3.f);
        float inv = rsqrtf(var + EPSF);
        t0 = fmaxf((u[0] - m) * inv * gp[0] + betap[0], 0.f);
        t1 = fmaxf((u[1] - m) * inv * gp[1] + betap[1], 0.f);
        t2 = fmaxf((u[2] - m) * inv * gp[2] + betap[2], 0.f);
    }

    const int obase = h * DH;

    // pe (packed)
    __attribute__((aligned(16))) h2 pe2[8];
    {
        h2 t02 = asH2(pk2(t0, t0));
        h2 t12 = asH2(pk2(t1, t1));
        h2 t22 = asH2(pk2(t2, t2));
        const uint* W0p = PK + PK_WP2 + 0 * 64 + h * 8;
        const uint* W1p = PK + PK_WP2 + 1 * 64 + h * 8;
        const uint* W2p = PK + PK_WP2 + 2 * 64 + h * 8;
        const uint* Bp  = PK + PK_BP2 + h * 8;
        #pragma unroll
        for (int i = 0; i < 8; ++i) {
            h2 acc = asH2(Bp[i]);
            acc = acc + t02 * asH2(W0p[i]);
            acc = acc + t12 * asH2(W1p[i]);
            acc = acc + t22 * asH2(W2p[i]);
            pe2[i] = acc;
        }
    }

    // gather q,k,v (f16 packed); r = k + pe - q; vp = v + pe (for contrib)
    __attribute__((aligned(16))) h2 vp2[8], r2[8];
    {
        __attribute__((aligned(16))) h2 k2[8], q2[8], v2[8];
        const uint4* k4 = (const uint4*)(xk + (size_t)j * OC + obase);
        const uint4* v4 = (const uint4*)(xv + (size_t)j * OC + obase);
        const uint4* q4 = (const uint4*)(xq + (size_t)n * OC + obase);
        *(uint4*)&k2[0] = k4[0]; *(uint4*)&k2[4] = k4[1];
        *(uint4*)&v2[0] = v4[0]; *(uint4*)&v2[4] = v4[1];
        *(uint4*)&q2[0] = q4[0]; *(uint4*)&q2[4] = q4[1];
        #pragma unroll
        for (int i = 0; i < 8; ++i) {
            r2[i]  = (k2[i] + pe2[i]) - q2[i];
            vp2[i] = v2[i] + pe2[i];
        }
    }

    // LN1 (packed) + relu -> a2
    __attribute__((aligned(16))) h2 a2[8];
    {
        h2 sum2 = r2[0];
        #pragma unroll
        for (int i = 1; i < 8; ++i) sum2 = sum2 + r2[i];
        float m = ((float)sum2[0] + (float)sum2[1]) * (1.f / DH);
        h2 m2 = asH2(pk2(m, m));
        h2 vs2 = {(__fp16)0.f, (__fp16)0.f};
        #pragma unroll
        for (int i = 0; i < 8; ++i) {
            r2[i] = r2[i] - m2;
            vs2 = vs2 + r2[i] * r2[i];
        }
        float var = ((float)vs2[0] + (float)vs2[1]) * (1.f / DH);
        float inv = rsqrtf(var + EPSF);
        h2 inv2 = asH2(pk2(inv, inv));
        h2 z2 = {(__fp16)0.f, (__fp16)0.f};
        #pragma unroll
        for (int i = 0; i < 8; ++i) {
            h2 gi = asH2(PK[PK_GW1 + i]) * inv2;
            a2[i] = PKMAX(r2[i] * gi + asH2(PK[PK_BW1P + i]), z2);
        }
    }

    // --- w1 = a @ Ww1 + bw1 via MFMA (wave-local LDS round trips) ---
    float w1v[16];
    {
        // stage a2: row = lane, 16 halfs, pitch 80 B (16-B aligned, <=2-way banks)
        *(uint4*)(aw + lane * 80 +  0) = *(uint4*)&a2[0];
        *(uint4*)(aw + lane * 80 + 16) = *(uint4*)&a2[4];

        const int c = lane & 15;
        const int q = lane >> 4;
        // A fragments: MFMA m covers rows m*16+c; k-halfs (q&1)*8.. (q>=2 lanes
        // read a valid slot; their B is zero so contents are don't-care)
        h8 af0 = *(h8*)(aw + (0 * 16 + c) * 80 + (q & 1) * 16);
        h8 af1 = *(h8*)(aw + (1 * 16 + c) * 80 + (q & 1) * 16);
        h8 af2 = *(h8*)(aw + (2 * 16 + c) * 80 + (q & 1) * 16);
        h8 af3 = *(h8*)(aw + (3 * 16 + c) * 80 + (q & 1) * 16);

        const float bw1c = FPK[PKF_BW1 + c];
        f32x4 acc0 = (f32x4){bw1c, bw1c, bw1c, bw1c};
        f32x4 acc1 = acc0, acc2m = acc0, acc3 = acc0;
        acc0  = __builtin_amdgcn_mfma_f32_16x16x32_f16(af0, bfrag, acc0,  0, 0, 0);
        acc1  = __builtin_amdgcn_mfma_f32_16x16x32_f16(af1, bfrag, acc1,  0, 0, 0);
        acc2m = __builtin_amdgcn_mfma_f32_16x16x32_f16(af2, bfrag, acc2m, 0, 0, 0);
        acc3  = __builtin_amdgcn_mfma_f32_16x16x32_f16(af3, bfrag, acc3,  0, 0, 0);

        // scatter C back: row = m*16 + q*4 + r, col = c  (f32, pitch 80 B)
        #pragma unroll
        for (int r = 0; r < 4; ++r) {
            *(float*)(aw + (0 * 16 + q * 4 + r) * 80 + c * 4) = acc0[r];
            *(float*)(aw + (1 * 16 + q * 4 + r) * 80 + c * 4) = acc1[r];
            *(float*)(aw + (2 * 16 + q * 4 + r) * 80 + c * 4) = acc2m[r];
            *(float*)(aw + (3 * 16 + q * 4 + r) * 80 + c * 4) = acc3[r];
        }
        // gather own row back
        #pragma unroll
        for (int i = 0; i < 4; ++i)
            *(f32x4*)&w1v[4 * i] = *(const f32x4*)(aw + lane * 80 + 16 * i);
    }

    // LN2 (packed) + relu, fused (@Ww2 + bw2).mean via rmean pairs
    float logit;
    {
        __attribute__((aligned(16))) h2 w2[8];
        #pragma unroll
        for (int i = 0; i < 8; ++i) w2[i] = asH2(pk2(w1v[2 * i], w1v[2 * i + 1]));
        h2 sum2 = w2[0];
        #pragma unroll
        for (int i = 1; i < 8; ++i) sum2 = sum2 + w2[i];
        float m = ((float)sum2[0] + (float)sum2[1]) * (1.f / OSH);
        h2 m2 = asH2(pk2(m, m));
        h2 vs2 = {(__fp16)0.f, (__fp16)0.f};
        #pragma unroll
        for (int i = 0; i < 8; ++i) {
            w2[i] = w2[i] - m2;
            vs2 = vs2 + w2[i] * w2[i];
        }
        float var = ((float)vs2[0] + (float)vs2[1]) * (1.f / OSH);
        float inv = rsqrtf(var + EPSF);
        h2 inv2 = asH2(pk2(inv, inv));
        h2 z2 = {(__fp16)0.f, (__fp16)0.f};
        logit = FPK[PKF_RMB];
        #pragma unroll
        for (int i = 0; i < 8; ++i) {
            h2 gi = asH2(PK[PK_GW2 + i]) * inv2;
            h2 bv2 = PKMAX(w2[i] * gi + asH2(PK[PK_BW2P + i]), z2);
            logit = __builtin_amdgcn_fdot2(bv2, asH2(PK[PK_RM + i]), logit, false);
        }
    }

    // softmax over s: 16-lane butterfly; division via v_rcp (den > 0 always)
    float w;
    {
        float mx = logit;
        #pragma unroll
        for (int mask = 1; mask < 16; mask <<= 1)
            mx = fmaxf(mx, __shfl_xor(mx, mask));
        float e = __expf(logit - mx);
        float den = e;
        #pragma unroll
        for (int mask = 1; mask < 16; mask <<= 1)
            den += __shfl_xor(den, mask);
        w = e * __builtin_amdgcn_rcpf(den);
    }

    // protect pool (a2/w1 regions) before overlaying s_c on it
    __syncthreads();

    // contrib (packed): c2 = (v2 + pe2) * w ; s_c[s][h*8..h*8+7] (pitch 68 uints)
    {
        h2 w2p = asH2(pk2(w, w));
        __attribute__((aligned(16))) h2 c2[8];
        #pragma unroll
        for (int i = 0; i < 8; ++i)
            c2[i] = vp2[i] * w2p;
        *(uint4*)(pool + s * 272 + h * 32)      = *(uint4*)&c2[0];
        *(uint4*)(pool + s * 272 + h * 32 + 16) = *(uint4*)&c2[4];
    }
    __syncthreads();

    // reduce over s: output element t = (head t>>4, d t&15); packed column sum
    {
        const int oh = t >> 4;
        const int od = t & 15;
        const int col = oh * 8 + (od >> 1);
        h2 acc2 = {(__fp16)0.f, (__fp16)0.f};
        #pragma unroll
        for (int ss = 0; ss < NS; ++ss)
            acc2 = acc2 + *(const h2*)(pool + ss * 272 + col * 4);
        out[(size_t)n * OC + t] = (float)acc2[od & 1];
    }
}

// ---------------------------------------------------------------------------
extern "C" void kernel_launch(void* const* d_in, const int* in_sizes, int n_in,
                              void* d_out, int out_size, void* d_ws, size_t ws_size,
                              hipStream_t stream) {
    const float* p     = (const float*)d_in[0];
    const float* x     = (const float*)d_in[1];
    const int*   idx   = (const int*)d_in[2];
    const float* Wq    = (const float*)d_in[3];
    const float* bq    = (const float*)d_in[4];
    const float* Wk    = (const float*)d_in[5];
    const float* bk    = (const float*)d_in[6];
    const float* Wv    = (const float*)d_in[7];
    const float* bv    = (const float*)d_in[8];
    const float* Wp1   = (const float*)d_in[9];
    const float* bp1   = (const float*)d_in[10];
    const float* gp    = (const float*)d_in[11];
    const float* betap = (const float*)d_in[12];
    const float* Wp2   = (const float*)d_in[13];
    const float* bp2   = (const float*)d_in[14];
    const float* gw1   = (const float*)d_in[15];
    const float* betaw1= (const float*)d_in[16];
    const float* Ww1   = (const float*)d_in[17];
    const float* bw1   = (const float*)d_in[18];
    const float* gw2   = (const float*)d_in[19];
    const float* betaw2= (const float*)d_in[20];
    const float* Ww2   = (const float*)d_in[21];
    const float* bw2   = (const float*)d_in[22];
    float* out = (float*)d_out;

    ushort* WT = (ushort*)d_ws;                        // 3*128*128 f16
    ushort* xq = WT + 3 * OC * CIN;                    // N*128 f16
    ushort* xk = xq + (size_t)NPTS * OC;
    ushort* xv = xk + (size_t)NPTS * OC;
    uint*   PACKS = (uint*)(xv + (size_t)NPTS * OC);   // 448 uints

    prep_kernel<<<25, 256, 0, stream>>>(Wq, Wk, Wv,
                                        Wp2, bp2, gw1, betaw1,
                                        Ww1, bw1, gw2, betaw2, Ww2, bw2,
                                        WT, PACKS);

    dim3 g1((NPTS + 127) / 128, 3);   // 235 x 3
    qkv_mfma<<<g1, 256, 0, stream>>>(x, WT, bq, bk, bv, xq, xk, xv);

    attn_kernel<<<NPTS, 128, 0, stream>>>(p, idx, xq, xk, xv,
                                          Wp1, bp1, gp, betap, Ww1,
                                          PACKS, out);
}

// Round 2
// 190.641 us; speedup vs baseline: 1.0109x; 1.0109x over previous
//
#include <hip/hip_runtime.h>
#include <math.h>

typedef unsigned int  uint;
typedef unsigned short ushort;

// Problem constants
constexpr int NPTS = 30000;
constexpr int CIN  = 128;
constexpr int OC   = 128;   // O
constexpr int NH   = 8;     // heads
constexpr int NS   = 16;    // neighbors
constexpr int DH   = 16;    // O/H
constexpr int OSH  = 16;    // O/SHARE
constexpr float EPSF = 1e-5f;

typedef __attribute__((ext_vector_type(8))) __fp16 h8;
typedef __attribute__((ext_vector_type(4))) float  f32x4;
typedef __attribute__((ext_vector_type(2))) __fp16 h2;

__device__ __forceinline__ ushort f2h(float f) {
    __fp16 h = (__fp16)f;
    return *(ushort*)&h;
}
__device__ __forceinline__ uint pk2(float a, float b) {
    h2 v = __builtin_amdgcn_cvt_pkrtz(a, b);
    return *(uint*)&v;
}
__device__ __forceinline__ h2 asH2(uint u) { return *(h2*)&u; }

#if defined(__has_builtin)
#if __has_builtin(__builtin_elementwise_max)
#define PKMAX(a, b) __builtin_elementwise_max(a, b)
#endif
#endif
#ifndef PKMAX
__device__ __forceinline__ h2 PKMAX(h2 a, h2 b) {
    h2 r; r[0] = a[0] > b[0] ? a[0] : b[0]; r[1] = a[1] > b[1] ? a[1] : b[1]; return r;
}
#endif

// PACKS layout (uints):
constexpr int PK_WW1   = 0;     // 128: pairs (Ww1[2dp][o], Ww1[2dp+1][o]) at [dp*16+o]
constexpr int PK_WP2   = 128;   // 192: c=0..2 pairs over o
constexpr int PK_BP2   = 320;   // 64
constexpr int PK_GW1   = 384;
constexpr int PK_BW1P  = 392;   // betaw1 pairs
constexpr int PK_GW2   = 400;
constexpr int PK_BW2P  = 408;   // betaw2 pairs
constexpr int PK_RM    = 416;   // rowmean(Ww2) pairs
constexpr int PKF_BW1  = 424;   // float view: bw1[16]
constexpr int PKF_RMB  = 440;   // float view: mean(bw2)

// ---------------------------------------------------------------------------
// Kernel 0: prep (unchanged).
// ---------------------------------------------------------------------------
__global__ __launch_bounds__(256) void prep_kernel(
    const float* __restrict__ Wq, const float* __restrict__ Wk, const float* __restrict__ Wv,
    const float* __restrict__ Wp2, const float* __restrict__ bp2,
    const float* __restrict__ gw1, const float* __restrict__ betaw1,
    const float* __restrict__ Ww1, const float* __restrict__ bw1,
    const float* __restrict__ gw2, const float* __restrict__ betaw2,
    const float* __restrict__ Ww2, const float* __restrict__ bw2,
    ushort* __restrict__ WT, uint* __restrict__ PK)
{
    const int b = blockIdx.x;
    const int t = threadIdx.x;
    if (b < 24) {
        const int mat = b >> 3;           // 0..2
        const int cg  = b & 7;            // col group of 16
        const float* W = (mat == 0) ? Wq : (mat == 1 ? Wk : Wv);
        const int col = cg * 16 + (t >> 4);
        const int k0  = (t & 15) * 8;
        float v0 = W[(k0 + 0) * OC + col], v1 = W[(k0 + 1) * OC + col];
        float v2 = W[(k0 + 2) * OC + col], v3 = W[(k0 + 3) * OC + col];
        float v4 = W[(k0 + 4) * OC + col], v5 = W[(k0 + 5) * OC + col];
        float v6 = W[(k0 + 6) * OC + col], v7 = W[(k0 + 7) * OC + col];
        uint4 u = make_uint4(pk2(v0, v1), pk2(v2, v3), pk2(v4, v5), pk2(v6, v7));
        *(uint4*)&WT[(size_t)mat * OC * CIN + (size_t)col * CIN + k0] = u;
    } else {
        float* FPK = (float*)PK;
        if (t < 128) {
            int dp = t >> 4, o = t & 15;
            PK[PK_WW1 + t] = pk2(Ww1[(2 * dp) * OSH + o], Ww1[(2 * dp + 1) * OSH + o]);
        }
        if (t < 192) {
            int c = t >> 6, jj = t & 63;
            PK[PK_WP2 + t] = pk2(Wp2[c * OC + 2 * jj], Wp2[c * OC + 2 * jj + 1]);
        }
        if (t < 64)
            PK[PK_BP2 + t] = pk2(bp2[2 * t], bp2[2 * t + 1]);
        if (t < 8) {
            PK[PK_GW1 + t]  = pk2(gw1[2 * t],    gw1[2 * t + 1]);
            PK[PK_BW1P + t] = pk2(betaw1[2 * t], betaw1[2 * t + 1]);
            PK[PK_GW2 + t]  = pk2(gw2[2 * t],    gw2[2 * t + 1]);
            PK[PK_BW2P + t] = pk2(betaw2[2 * t], betaw2[2 * t + 1]);
            float r0 = 0.f, r1 = 0.f;
            #pragma unroll
            for (int o2 = 0; o2 < OSH; ++o2) {
                r0 += Ww2[(2 * t) * OSH + o2];
                r1 += Ww2[(2 * t + 1) * OSH + o2];
            }
            PK[PK_RM + t] = pk2(r0 * (1.f / OSH), r1 * (1.f / OSH));
        }
        if (t < 16)
            FPK[PKF_BW1 + t] = bw1[t];
        if (t == 16) {
            float acc = 0.f;
            #pragma unroll
            for (int o2 = 0; o2 < OSH; ++o2) acc += bw2[o2];
            FPK[PKF_RMB] = acc * (1.f / OSH);
        }
    }
}

// ---------------------------------------------------------------------------
// Kernel 1: QKV projection via f16 MFMA (unchanged).
// ---------------------------------------------------------------------------
__global__ __launch_bounds__(256) void qkv_mfma(
    const float* __restrict__ x, const ushort* __restrict__ WT,
    const float* __restrict__ bq, const float* __restrict__ bk, const float* __restrict__ bv,
    ushort* __restrict__ yq, ushort* __restrict__ yk, ushort* __restrict__ yv)
{
    const int mat = blockIdx.y;
    const float* bias = (mat == 0) ? bq : (mat == 1 ? bk : bv);
    ushort* y         = (mat == 0) ? yq : (mat == 1 ? yk : yv);
    const ushort* T   = WT + (size_t)mat * OC * CIN;

    const int n0   = blockIdx.x * 128;
    const int t    = threadIdx.x;
    const int wave = t >> 6;
    const int lane = t & 63;
    const int m16  = lane & 15;
    const int quad = lane >> 4;

    f32x4 acc[2][8];
    #pragma unroll
    for (int mt = 0; mt < 2; ++mt)
        #pragma unroll
        for (int nt = 0; nt < 8; ++nt)
            acc[mt][nt] = (f32x4){0.f, 0.f, 0.f, 0.f};

    int r0i = n0 + wave * 32 + m16;      // A row for mt=0
    int r1i = r0i + 16;                  // A row for mt=1
    if (r0i > NPTS - 1) r0i = NPTS - 1;
    if (r1i > NPTS - 1) r1i = NPTS - 1;
    const float* arow0 = x + (size_t)r0i * CIN;
    const float* arow1 = x + (size_t)r1i * CIN;

    #pragma unroll
    for (int ks = 0; ks < 4; ++ks) {
        const int kb = ks * 32 + quad * 8;
        float4 f00 = *(const float4*)(arow0 + kb);
        float4 f01 = *(const float4*)(arow0 + kb + 4);
        float4 f10 = *(const float4*)(arow1 + kb);
        float4 f11 = *(const float4*)(arow1 + kb + 4);
        uint4 ua0 = make_uint4(pk2(f00.x, f00.y), pk2(f00.z, f00.w),
                               pk2(f01.x, f01.y), pk2(f01.z, f01.w));
        uint4 ua1 = make_uint4(pk2(f10.x, f10.y), pk2(f10.z, f10.w),
                               pk2(f11.x, f11.y), pk2(f11.z, f11.w));
        h8 a0 = *(h8*)&ua0;
        h8 a1 = *(h8*)&ua1;
        #pragma unroll
        for (int nt = 0; nt < 8; ++nt) {
            h8 bfr = *(const h8*)(T + (size_t)(nt * 16 + m16) * CIN + kb);
            acc[0][nt] = __builtin_amdgcn_mfma_f32_16x16x32_f16(a0, bfr, acc[0][nt], 0, 0, 0);
            acc[1][nt] = __builtin_amdgcn_mfma_f32_16x16x32_f16(a1, bfr, acc[1][nt], 0, 0, 0);
        }
    }

    #pragma unroll
    for (int mt = 0; mt < 2; ++mt) {
        #pragma unroll
        for (int nt = 0; nt < 8; ++nt) {
            const int col = nt * 16 + m16;
            const float bcol = bias[col];
            #pragma unroll
            for (int r = 0; r < 4; ++r) {
                int row = n0 + wave * 32 + mt * 16 + quad * 4 + r;
                if (row < NPTS)
                    y[(size_t)row * OC + col] = f2h(acc[mt][nt][r] + bcol);
            }
        }
    }
}

// ---------------------------------------------------------------------------
// Kernel 2: per-point attention — RESTRUCTURED this round.
// 1 wave per point (4 points per 256-thread block), NO barriers.
// lane = (u, s): s = lane&15 (neighbor), u = lane>>4; lane handles heads
// {2u, 2u+1} = halfs [32u..32u+31] of the 128-wide row. Per-(n,s) work
// (pr-MLP, idx/p loads) now replicated 4x instead of 8x; gathers are
// 64 B/lane. Heads processed sequentially to bound VGPRs. s-reduction via
// wave-local LDS (no __syncthreads — wave-synchronous, r1-verified pattern).
// dot2 math identical to round 0 (the verified fast VALU form).
// ---------------------------------------------------------------------------
__global__ __launch_bounds__(256) void attn_kernel(
    const float* __restrict__ p, const int* __restrict__ idx,
    const ushort* __restrict__ xq, const ushort* __restrict__ xk, const ushort* __restrict__ xv,
    const float* __restrict__ Wp1, const float* __restrict__ bp1,
    const float* __restrict__ gp,  const float* __restrict__ betap,
    const uint* __restrict__ PK,
    float* __restrict__ out)
{
    const int t    = threadIdx.x;   // 0..255
    const int wv   = t >> 6;        // point within block
    const int lane = t & 63;
    const int n    = blockIdx.x * 4 + wv;
    const int s    = lane & 15;     // neighbor
    const int u    = lane >> 4;     // head-pair 0..3 (heads 2u, 2u+1)

    const float* FPK = (const float*)PK;

    // wave-local reduction buffer: 16 rows (s) x 272 B (128 halfs + pad)
    __shared__ __attribute__((aligned(16))) char pool[4 * 16 * 272];
    char* red = pool + wv * (16 * 272);

    const int j = idx[n * NS + s];

    // inline pr-MLP (3-wide): u1 = pr @ Wp1 + bp1; LN3; relu  (4x replicated)
    float t0, t1, t2;
    {
        float pr0 = p[j * 3 + 0] - p[n * 3 + 0];
        float pr1 = p[j * 3 + 1] - p[n * 3 + 1];
        float pr2 = p[j * 3 + 2] - p[n * 3 + 2];
        float uu[3];
        #pragma unroll
        for (int c = 0; c < 3; ++c)
            uu[c] = bp1[c] + pr0 * Wp1[0 * 3 + c] + pr1 * Wp1[1 * 3 + c] + pr2 * Wp1[2 * 3 + c];
        float m   = (uu[0] + uu[1] + uu[2]) * (1.f / 3.f);
        float d0 = uu[0] - m, d1 = uu[1] - m, d2 = uu[2] - m;
        float var = (d0 * d0 + d1 * d1 + d2 * d2) * (1.f / 3.f);
        float inv = rsqrtf(var + EPSF);
        t0 = fmaxf((uu[0] - m) * inv * gp[0] + betap[0], 0.f);
        t1 = fmaxf((uu[1] - m) * inv * gp[1] + betap[1], 0.f);
        t2 = fmaxf((uu[2] - m) * inv * gp[2] + betap[2], 0.f);
    }

    // pe for the 2-head slice: pairs jj = u*16 + i, i = 0..15
    __attribute__((aligned(16))) h2 pe2[16];
    {
        h2 t02 = asH2(pk2(t0, t0));
        h2 t12 = asH2(pk2(t1, t1));
        h2 t22 = asH2(pk2(t2, t2));
        const uint* W0p = PK + PK_WP2 + 0 * 64 + u * 16;
        const uint* W1p = PK + PK_WP2 + 1 * 64 + u * 16;
        const uint* W2p = PK + PK_WP2 + 2 * 64 + u * 16;
        const uint* Bp  = PK + PK_BP2 + u * 16;
        #pragma unroll
        for (int i = 0; i < 16; ++i) {
            h2 acc = asH2(Bp[i]);
            acc = acc + t02 * asH2(W0p[i]);
            acc = acc + t12 * asH2(W1p[i]);
            acc = acc + t22 * asH2(W2p[i]);
            pe2[i] = acc;
        }
    }

    // gather q,k,v 64 B slices; r = k + pe - q; vp = v + pe
    __attribute__((aligned(16))) h2 vp2[16], r2[16];
    {
        __attribute__((aligned(16))) h2 k2[16], q2[16], v2[16];
        const uint4* k4 = (const uint4*)(xk + (size_t)j * OC + u * 32);
        const uint4* v4 = (const uint4*)(xv + (size_t)j * OC + u * 32);
        const uint4* q4 = (const uint4*)(xq + (size_t)n * OC + u * 32);
        #pragma unroll
        for (int i = 0; i < 4; ++i) {
            *(uint4*)&k2[4 * i] = k4[i];
            *(uint4*)&v2[4 * i] = v4[i];
            *(uint4*)&q2[4 * i] = q4[i];
        }
        #pragma unroll
        for (int i = 0; i < 16; ++i) {
            r2[i]  = (k2[i] + pe2[i]) - q2[i];
            vp2[i] = v2[i] + pe2[i];
        }
    }

    // per-head pipeline (sequential over the lane's 2 heads)
    float wgt[2];
    #pragma unroll
    for (int hh = 0; hh < 2; ++hh) {
        h2* rr = r2 + hh * 8;

        // LN1 (packed) + relu -> a2
        __attribute__((aligned(16))) h2 a2[8];
        {
            h2 sum2 = rr[0];
            #pragma unroll
            for (int i = 1; i < 8; ++i) sum2 = sum2 + rr[i];
            float m = ((float)sum2[0] + (float)sum2[1]) * (1.f / DH);
            h2 m2 = asH2(pk2(m, m));
            h2 vs2 = {(__fp16)0.f, (__fp16)0.f};
            #pragma unroll
            for (int i = 0; i < 8; ++i) {
                rr[i] = rr[i] - m2;
                vs2 = vs2 + rr[i] * rr[i];
            }
            float var = ((float)vs2[0] + (float)vs2[1]) * (1.f / DH);
            float inv = rsqrtf(var + EPSF);
            h2 inv2 = asH2(pk2(inv, inv));
            h2 z2 = {(__fp16)0.f, (__fp16)0.f};
            #pragma unroll
            for (int i = 0; i < 8; ++i) {
                h2 gi = asH2(PK[PK_GW1 + i]) * inv2;
                a2[i] = PKMAX(rr[i] * gi + asH2(PK[PK_BW1P + i]), z2);
            }
        }

        // w1 = a @ Ww1 + bw1 (fdot2)
        float w1[OSH];
        #pragma unroll
        for (int o2 = 0; o2 < OSH; ++o2) w1[o2] = FPK[PKF_BW1 + o2];
        #pragma unroll
        for (int dp = 0; dp < 8; ++dp) {
            #pragma unroll
            for (int o2 = 0; o2 < OSH; ++o2)
                w1[o2] = __builtin_amdgcn_fdot2(a2[dp], asH2(PK[PK_WW1 + dp * 16 + o2]), w1[o2], false);
        }

        // LN2 (packed) + relu, fused (@Ww2 + bw2).mean via rmean pairs
        float logit;
        {
            __attribute__((aligned(16))) h2 w2[8];
            #pragma unroll
            for (int i = 0; i < 8; ++i) w2[i] = asH2(pk2(w1[2 * i], w1[2 * i + 1]));
            h2 sum2 = w2[0];
            #pragma unroll
            for (int i = 1; i < 8; ++i) sum2 = sum2 + w2[i];
            float m = ((float)sum2[0] + (float)sum2[1]) * (1.f / OSH);
            h2 m2 = asH2(pk2(m, m));
            h2 vs2 = {(__fp16)0.f, (__fp16)0.f};
            #pragma unroll
            for (int i = 0; i < 8; ++i) {
                w2[i] = w2[i] - m2;
                vs2 = vs2 + w2[i] * w2[i];
            }
            float var = ((float)vs2[0] + (float)vs2[1]) * (1.f / OSH);
            float inv = rsqrtf(var + EPSF);
            h2 inv2 = asH2(pk2(inv, inv));
            h2 z2 = {(__fp16)0.f, (__fp16)0.f};
            logit = FPK[PKF_RMB];
            #pragma unroll
            for (int i = 0; i < 8; ++i) {
                h2 gi = asH2(PK[PK_GW2 + i]) * inv2;
                h2 bv2 = PKMAX(w2[i] * gi + asH2(PK[PK_BW2P + i]), z2);
                logit = __builtin_amdgcn_fdot2(bv2, asH2(PK[PK_RM + i]), logit, false);
            }
        }

        // softmax over s: 16-lane butterfly within the u-group
        {
            float mx = logit;
            #pragma unroll
            for (int mask = 1; mask < 16; mask <<= 1)
                mx = fmaxf(mx, __shfl_xor(mx, mask));
            float e = __expf(logit - mx);
            float den = e;
            #pragma unroll
            for (int mask = 1; mask < 16; mask <<= 1)
                den += __shfl_xor(den, mask);
            wgt[hh] = e * __builtin_amdgcn_rcpf(den);
        }
    }

    // contrib: c2 = (v + pe) * w(head); write to wave-local LDS row s
    {
        h2 w0p = asH2(pk2(wgt[0], wgt[0]));
        h2 w1p = asH2(pk2(wgt[1], wgt[1]));
        __attribute__((aligned(16))) h2 c2[16];
        #pragma unroll
        for (int i = 0; i < 16; ++i)
            c2[i] = vp2[i] * (i < 8 ? w0p : w1p);
        char* wr = red + s * 272 + u * 64;
        *(uint4*)(wr +  0) = *(uint4*)&c2[0];
        *(uint4*)(wr + 16) = *(uint4*)&c2[4];
        *(uint4*)(wr + 32) = *(uint4*)&c2[8];
        *(uint4*)(wr + 48) = *(uint4*)&c2[12];
    }

    __builtin_amdgcn_wave_barrier();   // ordering only; wave-synchronous LDS

    // reduce over s: lane owns out cols {2*lane, 2*lane+1} (pair index = lane)
    {
        h2 acc2 = {(__fp16)0.f, (__fp16)0.f};
        #pragma unroll
        for (int ss = 0; ss < NS; ++ss)
            acc2 = acc2 + *(const h2*)(red + ss * 272 + lane * 4);
        float2 o2 = make_float2((float)acc2[0], (float)acc2[1]);
        *(float2*)(out + (size_t)n * OC + lane * 2) = o2;
    }
}

// ---------------------------------------------------------------------------
extern "C" void kernel_launch(void* const* d_in, const int* in_sizes, int n_in,
                              void* d_out, int out_size, void* d_ws, size_t ws_size,
                              hipStream_t stream) {
    const float* p     = (const float*)d_in[0];
    const float* x     = (const float*)d_in[1];
    const int*   idx   = (const int*)d_in[2];
    const float* Wq    = (const float*)d_in[3];
    const float* bq    = (const float*)d_in[4];
    const float* Wk    = (const float*)d_in[5];
    const float* bk    = (const float*)d_in[6];
    const float* Wv    = (const float*)d_in[7];
    const float* bv    = (const float*)d_in[8];
    const float* Wp1   = (const float*)d_in[9];
    const float* bp1   = (const float*)d_in[10];
    const float* gp    = (const float*)d_in[11];
    const float* betap = (const float*)d_in[12];
    const float* Wp2   = (const float*)d_in[13];
    const float* bp2   = (const float*)d_in[14];
    const float* gw1   = (const float*)d_in[15];
    const float* betaw1= (const float*)d_in[16];
    const float* Ww1   = (const float*)d_in[17];
    const float* bw1   = (const float*)d_in[18];
    const float* gw2   = (const float*)d_in[19];
    const float* betaw2= (const float*)d_in[20];
    const float* Ww2   = (const float*)d_in[21];
    const float* bw2   = (const float*)d_in[22];
    float* out = (float*)d_out;

    ushort* WT = (ushort*)d_ws;                        // 3*128*128 f16
    ushort* xq = WT + 3 * OC * CIN;                    // N*128 f16
    ushort* xk = xq + (size_t)NPTS * OC;
    ushort* xv = xk + (size_t)NPTS * OC;
    uint*   PACKS = (uint*)(xv + (size_t)NPTS * OC);   // 448 uints

    prep_kernel<<<25, 256, 0, stream>>>(Wq, Wk, Wv,
                                        Wp2, bp2, gw1, betaw1,
                                        Ww1, bw1, gw2, betaw2, Ww2, bw2,
                                        WT, PACKS);

    dim3 g1((NPTS + 127) / 128, 3);   // 235 x 3
    qkv_mfma<<<g1, 256, 0, stream>>>(x, WT, bq, bk, bv, xq, xk, xv);

    attn_kernel<<<NPTS / 4, 256, 0, stream>>>(p, idx, xq, xk, xv,
                                              Wp1, bp1, gp, betap,
                                              PACKS, out);
}